// Round 2
// baseline (254.540 us; speedup 1.0000x reference)
//
#include <hip/hip_runtime.h>
#include <hip/hip_bf16.h>
#include <cstdint>

// Problem constants
#define B_DIM 16384
#define DX 256
#define DH 512
#define DS 128
#define DT 128
#define KDIM 1024   // DX+DH+DS+DT
#define NDIM 2048   // 4*DH
#define HOUT 512

#define NT 32        // K-tiles of BK=32
#define SLOT 8192    // ushorts per 16KB LDS slot (256 rows x 32 k x 2B)

typedef __attribute__((ext_vector_type(8))) short short8;
typedef __attribute__((ext_vector_type(4))) float floatx4;

union bf16x8 {
  short8 v;
  __hip_bfloat16 b[8];
};

__device__ __forceinline__ float fast_sigmoid(float x) {
  return 1.f / (1.f + __expf(-x));
}
__device__ __forceinline__ float fast_tanh(float x) {
  float e = __expf(-2.f * x);
  return (1.f - e) / (1.f + e);
}

// ===========================================================================
// A layout: row-major bf16 concat [B][1024]  (k: 0..255 x, 256..767 h,
//   768..895 s, 896..1023 t).
// W layout: row-major bf16 [pcol][1024], packed col order
//   pcol = nb*256 + wn*64 + g*16 + hl  <->  orig col = g*512 + (nb*64+wn*16+hl)
//   (g: 0=i,1=f,2=o,3=c~) so a wave's 64-col tile = 4 gates x 16 hh -> register
//   epilogue.
// GEMM stages both via global_load_lds with PER-LANE pre-swizzled global source
// addresses (LDS dest stays linear): LDS slot holds [row][32k] where the 16B
// k-chunk at linear position qlin contains global chunk qlin ^ ((row>>1)&3).
// Fragment reads apply the same XOR -> all 8 LDS bank-groups hit uniformly
// (kills the 8-way conflict of the naive 64B-row layout).
// ===========================================================================

__global__ __launch_bounds__(256) void pack_A(
    const float* __restrict__ x, const float* __restrict__ h,
    const float* __restrict__ s, const float* __restrict__ t,
    __hip_bfloat16* __restrict__ Ap) {
  int tid = blockIdx.x * 256 + threadIdx.x;  // 0 .. B_DIM*KDIM/8-1
  int r = tid >> 7;          // row 0..16383
  int k = (tid & 127) * 8;   // 0..1016
  const float* p;
  if (k < 768) {
    p = (k < 256) ? (x + (size_t)r * DX + k) : (h + (size_t)r * DH + (k - 256));
  } else {
    p = (k < 896) ? (s + (size_t)r * DS + (k - 768)) : (t + (size_t)r * DT + (k - 896));
  }
  floatx4 v0 = *(const floatx4*)p;
  floatx4 v1 = *(const floatx4*)(p + 4);
  bf16x8 o;
#pragma unroll
  for (int j = 0; j < 4; ++j) {
    o.b[j]     = __float2bfloat16(v0[j]);
    o.b[4 + j] = __float2bfloat16(v1[j]);
  }
  *(short8*)(Ap + (size_t)tid * 8) = o.v;
}

__global__ __launch_bounds__(256) void pack_W(
    const float* __restrict__ Wx, const float* __restrict__ Wh,
    const float* __restrict__ Ws, const float* __restrict__ Wt,
    __hip_bfloat16* __restrict__ Wp) {
  int tid = blockIdx.x * 256 + threadIdx.x;  // 0 .. NDIM*KDIM/8-1
  int pcol = tid >> 7;           // packed col 0..2047
  int k0 = (tid & 127) * 8;      // 0..1016
  int nb = pcol >> 8, rr = pcol & 255;
  int wn = rr >> 6, g = (rr >> 4) & 3, hl = rr & 15;
  int col = g * 512 + nb * 64 + wn * 16 + hl;
  const float* src; int kl;
  if (k0 < 256)      { src = Wx; kl = k0; }
  else if (k0 < 768) { src = Wh; kl = k0 - 256; }
  else if (k0 < 896) { src = Ws; kl = k0 - 768; }
  else               { src = Wt; kl = k0 - 896; }
  bf16x8 o;
#pragma unroll
  for (int r = 0; r < 8; ++r)
    o.b[r] = __float2bfloat16(src[(size_t)(kl + r) * NDIM + col]);
  *(short8*)(Wp + (size_t)tid * 8) = o.v;  // Wp[pcol][k0..k0+7]
}

// ---------------------------------------------------------------------------
// 256x256 tile, BK=32, 8 waves (2M x 4N), 3-slot LDS ring, counted-vmcnt
// phase schedule (T2 swizzle + T3/T4 counted pipeline + T5 setprio).
// Per K-tile: 2 phases x {ds_read frags | 2x global_load_lds stage | barrier |
// 16 MFMA}; tile end: s_waitcnt vmcnt(4) + barrier (tile t+1 validated, tile
// t+2's 4 loads stay in flight). Stage slot (t+2)%3 was freed at end of t-1.
// ---------------------------------------------------------------------------
#define GLD(src, dst)                                              \
  __builtin_amdgcn_global_load_lds(                                \
      (const __attribute__((address_space(1))) void*)(src),        \
      (__attribute__((address_space(3))) void*)(dst), 16, 0, 0)

__global__ __launch_bounds__(512, 2) void lstm_gemm(
    const __hip_bfloat16* __restrict__ Ap, const __hip_bfloat16* __restrict__ Wp,
    const float* __restrict__ bh, const float* __restrict__ c_in,
    float* __restrict__ out) {
  extern __shared__ unsigned short smem[];   // 96 KB
  unsigned short* As = smem;                 // 3 slots x 8192
  unsigned short* Bs = smem + 3 * SLOT;      // 3 slots x 8192

  const int tid = threadIdx.x;
  const int lane = tid & 63;
  const int wid = tid >> 6;      // 0..7
  const int wm = wid & 1;        // row half (128 rows)
  const int wn = wid >> 1;       // col quarter (64 packed cols)
  const int q = lane >> 4;
  const int fr = lane & 15;

  // XCD-aware bijective swizzle (512 blocks, 512%8==0)
  const int bid = blockIdx.x;
  const int wg = (bid & 7) * 64 + (bid >> 3);
  const int mb = wg >> 3;        // 0..63
  const int nb = wg & 7;         // 0..7
  const int m0 = mb * 256;

  // Fragment read offsets (ushort idx within slot), XOR-swizzled
  int aOff[8], bOff[4];
#pragma unroll
  for (int m = 0; m < 8; ++m) {
    int row = wm * 128 + m * 16 + fr;
    aOff[m] = row * 32 + (q ^ ((row >> 1) & 3)) * 8;
  }
#pragma unroll
  for (int n = 0; n < 4; ++n) {
    int colc = wn * 64 + n * 16 + fr;
    bOff[n] = colc * 32 + (q ^ ((colc >> 1) & 3)) * 8;
  }

  // Per-lane pre-swizzled global source addresses for staging.
  // Each wave stages 16 rows per half; lane covers row srow + lane/4,
  // 16B k-chunk qlin=lane&3; source chunk = qlin ^ ((row>>1)&3).
  const int srow = wid * 16 + (lane >> 2);     // 0..127
  const int qlin = lane & 3;
  const int q0 = qlin ^ ((srow >> 1) & 3);
  const int srow1 = srow + 128;
  const int q1 = qlin ^ ((srow1 >> 1) & 3);
  const __hip_bfloat16* aS0 = Ap + (size_t)(m0 + srow)  * KDIM + q0 * 8;
  const __hip_bfloat16* aS1 = Ap + (size_t)(m0 + srow1) * KDIM + q1 * 8;
  const __hip_bfloat16* bS0 = Wp + (size_t)(nb * 256 + srow)  * KDIM + q0 * 8;
  const __hip_bfloat16* bS1 = Wp + (size_t)(nb * 256 + srow1) * KDIM + q1 * 8;

  const int dH0 = wid * 512;          // LDS dest base (ushort idx), half 0
  const int dH1 = 4096 + wid * 512;   // half 1

  floatx4 acc[8][4];
#pragma unroll
  for (int i = 0; i < 8; ++i)
#pragma unroll
    for (int j = 0; j < 4; ++j) acc[i][j] = (floatx4)0.f;

  // ---- Prologue: stage tiles 0 (slot 0) and 1 (slot 1) ----
  GLD(aS0,      &As[dH0]);        GLD(aS1,      &As[dH1]);
  GLD(bS0,      &Bs[dH0]);        GLD(bS1,      &Bs[dH1]);
  GLD(aS0 + 32, &As[SLOT + dH0]); GLD(aS1 + 32, &As[SLOT + dH1]);
  GLD(bS0 + 32, &Bs[SLOT + dH0]); GLD(bS1 + 32, &Bs[SLOT + dH1]);
  asm volatile("s_waitcnt vmcnt(4)\n\ts_barrier" ::: "memory");  // tile 0 landed

  int sR = 0;          // read slot offset (tile t)
  int sS = 2 * SLOT;   // stage slot offset (tile t+2)

  for (int t = 0; t < NT; ++t) {
    // Tail: clamp to re-stage tile 31's own data (same bytes -> benign).
    const int ts = (t < NT - 2) ? (t + 2) : (NT - 1);
    const int kO = ts * 32;
    const unsigned short* Ar = As + sR;
    const unsigned short* Br = Bs + sR;

    // ---- phase 0: A-frags m0..3 + all B-frags; stage A halves of t+2 ----
    short8 a0[4], bv[4];
#pragma unroll
    for (int m = 0; m < 4; ++m) a0[m] = *(const short8*)(Ar + aOff[m]);
#pragma unroll
    for (int n = 0; n < 4; ++n) bv[n] = *(const short8*)(Br + bOff[n]);
    GLD(aS0 + kO, &As[sS + dH0]);
    GLD(aS1 + kO, &As[sS + dH1]);
    asm volatile("s_barrier" ::: "memory");
    __builtin_amdgcn_sched_barrier(0);
    __builtin_amdgcn_s_setprio(1);
#pragma unroll
    for (int m = 0; m < 4; ++m)
#pragma unroll
      for (int n = 0; n < 4; ++n)
        acc[m][n] = __builtin_amdgcn_mfma_f32_16x16x32_bf16(a0[m], bv[n],
                                                            acc[m][n], 0, 0, 0);
    __builtin_amdgcn_s_setprio(0);
    asm volatile("s_barrier" ::: "memory");

    // ---- phase 1: A-frags m4..7; stage B halves of t+2 ----
    short8 a1[4];
#pragma unroll
    for (int m = 0; m < 4; ++m) a1[m] = *(const short8*)(Ar + aOff[4 + m]);
    GLD(bS0 + kO, &Bs[sS + dH0]);
    GLD(bS1 + kO, &Bs[sS + dH1]);
    asm volatile("s_barrier" ::: "memory");
    __builtin_amdgcn_sched_barrier(0);
    __builtin_amdgcn_s_setprio(1);
#pragma unroll
    for (int m = 0; m < 4; ++m)
#pragma unroll
      for (int n = 0; n < 4; ++n)
        acc[4 + m][n] = __builtin_amdgcn_mfma_f32_16x16x32_bf16(a1[m], bv[n],
                                                                acc[4 + m][n], 0, 0, 0);
    __builtin_amdgcn_s_setprio(0);
    // Tile end: validate tile t+1 (drain its 4 loads), keep t+2's 4 in flight.
    asm volatile("s_waitcnt vmcnt(4)\n\ts_barrier" ::: "memory");

    sR = (sR == 2 * SLOT) ? 0 : sR + SLOT;
    sS = (sS == 2 * SLOT) ? 0 : sS + SLOT;
  }

  // ---- In-register epilogue ----
  // acc[mi][g]: rows m0 + wm*128 + mi*16 + q*4 + r, gate g of hidden hh.
  const int hh = nb * 64 + wn * 16 + fr;
  float bias[4];
#pragma unroll
  for (int g = 0; g < 4; ++g) bias[g] = bh[g * 512 + hh];

#pragma unroll
  for (int mi = 0; mi < 8; ++mi) {
#pragma unroll
    for (int r = 0; r < 4; ++r) {
      const size_t grow = (size_t)(m0 + wm * 128 + mi * 16 + q * 4 + r);
      const float pi = acc[mi][0][r] + bias[0];
      const float pf = acc[mi][1][r] + bias[1];
      const float po = acc[mi][2][r] + bias[2];
      const float pc = acc[mi][3][r] + bias[3];
      const float ig = fast_sigmoid(pi);
      const float fg = fast_sigmoid(pf);
      const float og = fast_sigmoid(po);
      const float cg = fast_tanh(pc);
      const float cc = fg * c_in[grow * HOUT + hh] + ig * cg;
      out[grow * HOUT + hh] = fast_tanh(og * cc);  // faithful: tanh(o*c_new)
      out[(size_t)B_DIM * HOUT + grow * HOUT + hh] = cc;
    }
  }
}

// ---------------------------------------------------------------------------
extern "C" void kernel_launch(void* const* d_in, const int* in_sizes, int n_in,
                              void* d_out, int out_size, void* d_ws, size_t ws_size,
                              hipStream_t stream) {
  const float* x  = (const float*)d_in[0];
  const float* h  = (const float*)d_in[1];
  const float* c  = (const float*)d_in[2];
  const float* sp = (const float*)d_in[3];
  const float* tp = (const float*)d_in[4];
  const float* Wx = (const float*)d_in[5];
  const float* Wh = (const float*)d_in[6];
  const float* bh = (const float*)d_in[7];
  const float* Ws = (const float*)d_in[8];
  const float* Wt = (const float*)d_in[9];
  float* out = (float*)d_out;

  __hip_bfloat16* Ap = (__hip_bfloat16*)d_ws;                                     // 32 MB
  __hip_bfloat16* Wp = (__hip_bfloat16*)((char*)d_ws + (size_t)B_DIM * KDIM * 2); // 4 MB

  static bool attr_done = false;
  if (!attr_done) {
    hipFuncSetAttribute((const void*)lstm_gemm,
                        hipFuncAttributeMaxDynamicSharedMemorySize, 98304);
    attr_done = true;
  }

  pack_A<<<dim3(B_DIM * KDIM / 8 / 256), dim3(256), 0, stream>>>(x, h, sp, tp, Ap);
  pack_W<<<dim3(NDIM * KDIM / 8 / 256), dim3(256), 0, stream>>>(Wx, Wh, Ws, Wt, Wp);
  lstm_gemm<<<dim3(512), dim3(512), 98304, stream>>>(Ap, Wp, bh, c, out);
}